// Round 10
// baseline (74.634 us; speedup 1.0000x reference)
//
#include <hip/hip_runtime.h>

#define CSC 2.88539008177792681f  // 2*log2(e)

typedef float v2f __attribute__((ext_vector_type(2)));

__device__ __forceinline__ float fast_exp2(float x) {
  return __builtin_amdgcn_exp2f(x);
}
__device__ __forceinline__ float fast_rcp(float x) {
  return __builtin_amdgcn_rcpf(x);
}
__device__ __forceinline__ v2f vfma(v2f a, v2f b, v2f c) {
  return __builtin_elementwise_fma(a, b, c);
}
__device__ __forceinline__ v2f vsplat(float s) {
  v2f r;
  r[0] = s;
  r[1] = s;
  return r;
}
__device__ __forceinline__ float rdlane(float v, int l) {
  return __int_as_float(__builtin_amdgcn_readlane(__float_as_int(v), l));
}

// Projection: 256 blocks x 256 threads. Blocks 0..127 -> Eq row-major
// [qrow][e]; 128..255 -> EkT4 interleaved-transposed [e/4][col][4] so the
// attention score loop reads one float4 (4 e-values for its k) per e-quad,
// fully coalesced over k.
__global__ __launch_bounds__(256) void proj_kernel(
    const float* __restrict__ query, const float* __restrict__ key,
    const float* __restrict__ weight, float* __restrict__ Eq,
    float* __restrict__ EkT4) {
  __shared__ __align__(16) float rows[16][128];
  __shared__ __align__(16) float tile[16][132];  // +4 pad: conflict-free reads
  int blk = blockIdx.x;
  bool isK = blk >= 128;
  const float* src = isK ? key : query;
  int woff = isK ? 128 : 0;
  int row0 = (isK ? blk - 128 : blk) * 16;
  int tid = threadIdx.x;
#pragma unroll
  for (int i = 0; i < 8; ++i) {
    int f = i * 256 + tid;
    rows[f >> 7][f & 127] = src[(size_t)row0 * 128 + f];
  }
  __syncthreads();
  int e = tid & 127;
  int rh = (tid >> 7) * 8;  // wave-uniform
  float acc[8];
#pragma unroll
  for (int i = 0; i < 8; ++i) acc[i] = 0.f;
  const float4* wrow =
      reinterpret_cast<const float4*>(weight + (size_t)e * 256 + woff);
#pragma unroll 4
  for (int d4 = 0; d4 < 32; ++d4) {
    float4 wv = wrow[d4];
#pragma unroll
    for (int i = 0; i < 8; ++i) {
      float4 rv = *reinterpret_cast<const float4*>(&rows[rh + i][d4 * 4]);
      acc[i] = fmaf(rv.x, wv.x, acc[i]);
      acc[i] = fmaf(rv.y, wv.y, acc[i]);
      acc[i] = fmaf(rv.z, wv.z, acc[i]);
      acc[i] = fmaf(rv.w, wv.w, acc[i]);
    }
  }
  if (!isK) {
#pragma unroll
    for (int i = 0; i < 8; ++i)
      Eq[(size_t)(row0 + rh + i) * 128 + e] = fast_exp2(CSC * acc[i]);
  } else {
#pragma unroll
    for (int i = 0; i < 8; ++i) tile[rh + i][e] = fast_exp2(CSC * acc[i]);
    __syncthreads();
    int kk = tid & 15;
    int e4a = tid >> 4;  // 0..15
#pragma unroll
    for (int h = 0; h < 2; ++h) {
      int ee = e4a + h * 16;  // e-quad index 0..31
      float4 v = *reinterpret_cast<const float4*>(&tile[kk][ee * 4]);
      *reinterpret_cast<float4*>(EkT4 + ((size_t)ee * 2048 + row0 + kk) * 4) =
          v;
    }
  }
}

// Attention partials: BARRIER-FREE, LDS-FREE. 2048 blocks x 256 threads
// (8 blocks/CU, 32 waves/CU). Wave = independent unit: 4 q-rows x 64-k slice
// x 128 e. gwid = blk*4+w; qg = gwid>>4 (512 groups of 4 rows), ks = gwid&15
// (16 k-slices of 64). Thread = 4 q x 1 k (k = k0+lane).
// score' = -2*sum_e vT_e/(1+Eq*Ek) via n=2 reciprocal pairing (3 VALU +
// 0.5 rcp per element; rcp rides the trans pipe). sum(vT) cancels in softmax;
// scores bounded -> no max pass. p stays in registers; PV broadcasts p via
// v_readlane (SGPR-operand fma). Writes unnormalized PV partials + exp-sums.
__global__ __launch_bounds__(256, 8) void attn_kernel(
    const float* __restrict__ Eq, const float* __restrict__ EkT4,
    const float* __restrict__ vT, const float* __restrict__ value,
    float* __restrict__ pblk, float* __restrict__ dsum) {
  int tid = threadIdx.x;
  int lane = tid & 63;
  int gwid = blockIdx.x * 4 + (tid >> 6);
  int qg = gwid >> 4;        // 0..511
  int ks = gwid & 15;        // k-slice
  int b = qg >> 8;           // batch
  int q0 = (qg & 255) * 4;   // first q row
  int k0 = ks * 64;

  // ---- scores + exp + row partial sums: thread -> k = k0 + lane ----
  float p[4];
  {
    const float4* ekp =
        reinterpret_cast<const float4*>(EkT4) + (size_t)b * 1024 + k0 + lane;
    const float* eqb = Eq + ((size_t)b * 1024 + q0) * 128;  // wave-uniform
    const float4* vtp = reinterpret_cast<const float4*>(vT);
    float acc[4] = {0.f, 0.f, 0.f, 0.f};
#pragma unroll 2
    for (int e4 = 0; e4 < 32; ++e4) {
      float4 ek = ekp[(size_t)e4 * 2048];  // streamed, coalesced
      float4 vt4 = vtp[e4];                // uniform -> s_load
#pragma unroll
      for (int q = 0; q < 4; ++q) {
        float4 eqq = *reinterpret_cast<const float4*>(
            eqb + (size_t)q * 128 + e4 * 4);  // uniform -> s_load
        float A0 = fmaf(eqq.x, ek.x, 1.f);
        float A1 = fmaf(eqq.y, ek.y, 1.f);
        float n0 = fmaf(vt4.x, A1, vt4.y * A0);
        acc[q] = fmaf(n0, fast_rcp(A0 * A1), acc[q]);
        float A2 = fmaf(eqq.z, ek.z, 1.f);
        float A3 = fmaf(eqq.w, ek.w, 1.f);
        float n1 = fmaf(vt4.z, A3, vt4.w * A2);
        acc[q] = fmaf(n1, fast_rcp(A2 * A3), acc[q]);
      }
    }
#pragma unroll
    for (int q = 0; q < 4; ++q) {
      p[q] = fast_exp2(-CSC * acc[q]);
      float s = p[q];
#pragma unroll
      for (int off = 32; off; off >>= 1) s += __shfl_xor(s, off);
      if (lane == 0) dsum[(size_t)gwid * 4 + q] = s;
    }
  }

  // ---- PV partial over own k-slice: lane -> v2f column; p broadcast via
  //      v_readlane (kk is wave-uniform -> SGPR lane select) ----
  {
    v2f acc2[4];
#pragma unroll
    for (int q = 0; q < 4; ++q) acc2[q] = vsplat(0.f);
    const v2f* vp = reinterpret_cast<const v2f*>(value) +
                    ((size_t)b * 1024 + k0) * 64 + lane;
#pragma unroll 2
    for (int kg = 0; kg < 16; ++kg) {
      v2f vv0 = vp[(size_t)(kg * 4 + 0) * 64];
      v2f vv1 = vp[(size_t)(kg * 4 + 1) * 64];
      v2f vv2 = vp[(size_t)(kg * 4 + 2) * 64];
      v2f vv3 = vp[(size_t)(kg * 4 + 3) * 64];
#pragma unroll
      for (int q = 0; q < 4; ++q) {
        acc2[q] = vfma(vsplat(rdlane(p[q], kg * 4 + 0)), vv0, acc2[q]);
        acc2[q] = vfma(vsplat(rdlane(p[q], kg * 4 + 1)), vv1, acc2[q]);
        acc2[q] = vfma(vsplat(rdlane(p[q], kg * 4 + 2)), vv2, acc2[q]);
        acc2[q] = vfma(vsplat(rdlane(p[q], kg * 4 + 3)), vv3, acc2[q]);
      }
    }
#pragma unroll
    for (int q = 0; q < 4; ++q)
      *reinterpret_cast<v2f*>(pblk + (size_t)gwid * 512 + q * 128 + 2 * lane) =
          acc2[q];
  }
}

// Combine: sum the 16 k-slice partials per row, normalize.
// 512 blocks x 256 threads; thread -> one (row, v2f col) of out[2048][128].
// row is wave-uniform -> dsum loads become s_load.
__global__ __launch_bounds__(256) void combine_kernel(
    const float* __restrict__ pblk, const float* __restrict__ dsum,
    float* __restrict__ out) {
  int g = blockIdx.x * 256 + threadIdx.x;
  int row = g >> 6;  // 0..2047, wave-uniform
  int c = g & 63;
  int qg = row >> 2;
  int q = row & 3;
  int g0 = qg * 16;
  v2f r = vsplat(0.f);
  float d = 0.f;
#pragma unroll
  for (int ks = 0; ks < 16; ++ks) {
    r = r + *reinterpret_cast<const v2f*>(pblk + (size_t)(g0 + ks) * 512 +
                                          q * 128 + 2 * c);
    d += dsum[(size_t)(g0 + ks) * 4 + q];
  }
  float inv = fast_rcp(d);
  r[0] *= inv;
  r[1] *= inv;
  *reinterpret_cast<v2f*>(out + (size_t)row * 128 + 2 * c) = r;
}

extern "C" void kernel_launch(void* const* d_in, const int* in_sizes, int n_in,
                              void* d_out, int out_size, void* d_ws,
                              size_t ws_size, hipStream_t stream) {
  const float* query = (const float*)d_in[0];
  const float* key = (const float*)d_in[1];
  const float* value = (const float*)d_in[2];
  const float* vT = (const float*)d_in[3];
  const float* weight = (const float*)d_in[4];
  float* out = (float*)d_out;
  float* Eq = (float*)d_ws;      // 2048*128 f32 = 1 MB
  float* EkT4 = Eq + 262144;     // 32 x 2048 x 4 f32 = 1 MB (interleaved-T)
  float* pblk = EkT4 + 262144;   // 8192 waves x 4 x 128 f32 = 16 MB
  float* dsum = pblk + 4194304;  // 8192 x 4 f32 = 128 KB
  proj_kernel<<<256, 256, 0, stream>>>(query, key, weight, Eq, EkT4);
  attn_kernel<<<2048, 256, 0, stream>>>(Eq, EkT4, vT, value, pblk, dsum);
  combine_kernel<<<512, 256, 0, stream>>>(pblk, dsum, out);
}

// Round 11
// 50.529 us; speedup vs baseline: 1.4771x; 1.4771x over previous
//
#include <hip/hip_runtime.h>

#define CSC 2.88539008177792681f  // 2*log2(e)

typedef float v2f __attribute__((ext_vector_type(2)));

__device__ __forceinline__ float fast_exp2(float x) {
  return __builtin_amdgcn_exp2f(x);
}
__device__ __forceinline__ float fast_rcp(float x) {
  return __builtin_amdgcn_rcpf(x);
}
__device__ __forceinline__ v2f vfma(v2f a, v2f b, v2f c) {
  return __builtin_elementwise_fma(a, b, c);
}
__device__ __forceinline__ v2f vsplat(float s) {
  v2f r;
  r[0] = s;
  r[1] = s;
  return r;
}
__device__ __forceinline__ v2f f4lo(const float4& a) {
  v2f r;
  r[0] = a.x;
  r[1] = a.y;
  return r;
}
__device__ __forceinline__ v2f f4hi(const float4& a) {
  v2f r;
  r[0] = a.z;
  r[1] = a.w;
  return r;
}

// Projection: 256 blocks x 256 threads. Blocks 0..127 -> Eq row-major
// [qrow][e]; 128..255 -> EkT2 pair-interleaved transpose: float4 at
// [e2][kp] = (Ek[2e2][2kp], Ek[2e2][2kp+1], Ek[2e2+1][2kp], Ek[2e2+1][2kp+1]).
// One coalesced 16B load in the score loop covers a 2e x 2k block.
__global__ __launch_bounds__(256) void proj_kernel(
    const float* __restrict__ query, const float* __restrict__ key,
    const float* __restrict__ weight, float* __restrict__ Eq,
    float* __restrict__ EkT2) {
  __shared__ __align__(16) float rows[16][128];
  __shared__ __align__(16) float tile[16][132];  // +4 pad
  int blk = blockIdx.x;
  bool isK = blk >= 128;
  const float* src = isK ? key : query;
  int woff = isK ? 128 : 0;
  int row0 = (isK ? blk - 128 : blk) * 16;
  int tid = threadIdx.x;
#pragma unroll
  for (int i = 0; i < 8; ++i) {
    int f = i * 256 + tid;
    rows[f >> 7][f & 127] = src[(size_t)row0 * 128 + f];
  }
  __syncthreads();
  int e = tid & 127;
  int rh = (tid >> 7) * 8;  // wave-uniform
  float acc[8];
#pragma unroll
  for (int i = 0; i < 8; ++i) acc[i] = 0.f;
  const float4* wrow =
      reinterpret_cast<const float4*>(weight + (size_t)e * 256 + woff);
#pragma unroll 4
  for (int d4 = 0; d4 < 32; ++d4) {
    float4 wv = wrow[d4];
#pragma unroll
    for (int i = 0; i < 8; ++i) {
      float4 rv = *reinterpret_cast<const float4*>(&rows[rh + i][d4 * 4]);
      acc[i] = fmaf(rv.x, wv.x, acc[i]);
      acc[i] = fmaf(rv.y, wv.y, acc[i]);
      acc[i] = fmaf(rv.z, wv.z, acc[i]);
      acc[i] = fmaf(rv.w, wv.w, acc[i]);
    }
  }
  if (!isK) {
#pragma unroll
    for (int i = 0; i < 8; ++i)
      Eq[(size_t)(row0 + rh + i) * 128 + e] = fast_exp2(CSC * acc[i]);
  } else {
#pragma unroll
    for (int i = 0; i < 8; ++i) tile[rh + i][e] = fast_exp2(CSC * acc[i]);
    __syncthreads();
    int kpl = tid & 7;        // k-pair 0..7 within the 16-row tile
    int e2b = tid >> 3;       // 0..31
#pragma unroll
    for (int h = 0; h < 2; ++h) {
      int e2 = e2b + h * 32;  // 0..63
      float4 v = make_float4(tile[2 * kpl][2 * e2], tile[2 * kpl + 1][2 * e2],
                             tile[2 * kpl][2 * e2 + 1],
                             tile[2 * kpl + 1][2 * e2 + 1]);
      *reinterpret_cast<float4*>(
          EkT2 + ((size_t)e2 * 1024 + (row0 >> 1) + kpl) * 4) = v;
    }
  }
}

// 4-way reciprocal combine over an e-quad, v2f (pk) wide over a k-pair.
// sum_e vT_e/(1+eq_e*ek_e) = num/den; all A>=1, den<=2^84, f32-safe.
__device__ __forceinline__ void quad4pk(const float4 eq, const float4 vt,
                                        v2f ek0, v2f ek1, v2f ek2, v2f ek3,
                                        v2f& acc) {
  v2f one = vsplat(1.f);
  v2f A0 = vfma(vsplat(eq.x), ek0, one);
  v2f A1 = vfma(vsplat(eq.y), ek1, one);
  v2f A2 = vfma(vsplat(eq.z), ek2, one);
  v2f A3 = vfma(vsplat(eq.w), ek3, one);
  v2f P01 = A0 * A1;
  v2f P23 = A2 * A3;
  v2f t01 = vfma(vsplat(vt.x), A1, vsplat(vt.y) * A0);
  v2f t23 = vfma(vsplat(vt.z), A3, vsplat(vt.w) * A2);
  v2f num = vfma(t23, P01, t01 * P23);
  v2f den = P01 * P23;
  v2f r;
  r[0] = fast_rcp(den[0]);
  r[1] = fast_rcp(den[1]);
  acc = vfma(num, r, acc);
}

// Attention partial: grid 1024 = b(2) x qg(256) x kh(2); 256 threads (4 waves)
// Block = 4 q-rows x 512-k slice; thread = 4 q x 2 k (v2f pk math) x 128 e.
// eq/vT block-uniform -> s_load. 4 blocks/CU (16 waves) -> phase-offset blocks
// overlap score-VALU with PV's DS broadcasts. Writes UNNORMALIZED PV partials
// + exp-sums. score' = -2*sum_e vT_e/(1+Eq*Ek); sum(vT) cancels in softmax;
// scores bounded (|.|<=~18) -> no max pass.
__global__ __launch_bounds__(256, 4) void attn_kernel(
    const float* __restrict__ Eq, const float* __restrict__ EkT2,
    const float* __restrict__ vT, const float* __restrict__ value,
    float* __restrict__ pblk, float* __restrict__ dsum) {
  __shared__ __align__(16) float sc[4][512];    // 8 KB p-values
  __shared__ __align__(16) v2f pout[4][4][64];  // 8 KB PV partials
  __shared__ float wsum[4][4];

  int tid = threadIdx.x;
  int lane = tid & 63;
  int w = tid >> 6;
  int bi = blockIdx.x;
  int kh = bi & 1;
  int qg = (bi >> 1) & 255;
  int b = bi >> 9;
  int q0 = qg * 4;
  int k0 = kh * 512;

  // ---- scores + exp + row partial sums: thread -> k-pair kp = tid ----
  {
    const float4* ekp = reinterpret_cast<const float4*>(EkT2) +
                        (size_t)b * 512 + (k0 >> 1) + tid;
    const float* eqb = Eq + (size_t)(b * 1024 + q0) * 128;  // block-uniform
    const float4* vtp = reinterpret_cast<const float4*>(vT);
    v2f acc[4];
#pragma unroll
    for (int q = 0; q < 4; ++q) acc[q] = vsplat(0.f);
#pragma unroll 2
    for (int e4 = 0; e4 < 32; ++e4) {
      float4 f4a = ekp[(size_t)(2 * e4 + 0) * 1024];  // (e,e+1) x (k,k+1)
      float4 f4b = ekp[(size_t)(2 * e4 + 1) * 1024];  // (e+2,e+3) x (k,k+1)
      v2f ek0 = f4lo(f4a), ek1 = f4hi(f4a), ek2 = f4lo(f4b), ek3 = f4hi(f4b);
      float4 vt4 = vtp[e4];  // uniform -> s_load
#pragma unroll
      for (int q = 0; q < 4; ++q) {
        float4 eqq = *reinterpret_cast<const float4*>(
            eqb + (size_t)q * 128 + e4 * 4);  // uniform -> s_load
        quad4pk(eqq, vt4, ek0, ek1, ek2, ek3, acc[q]);
      }
    }
#pragma unroll
    for (int q = 0; q < 4; ++q) {
      v2f p;
      p[0] = fast_exp2(-CSC * acc[q][0]);
      p[1] = fast_exp2(-CSC * acc[q][1]);
      *reinterpret_cast<v2f*>(&sc[q][2 * tid]) = p;
      float s = p[0] + p[1];
#pragma unroll
      for (int off = 32; off; off >>= 1) s += __shfl_xor(s, off);
      if (lane == 0) wsum[w][q] = s;
    }
  }
  __syncthreads();
  if (tid < 4)
    dsum[(size_t)bi * 4 + tid] =
        wsum[0][tid] + wsum[1][tid] + wsum[2][tid] + wsum[3][tid];

  // ---- PV partial: wave w -> local k in [w*128,+128), all 4 q;
  //      lane -> v2f column; p broadcast via ds_read_b128 ----
  {
    int kb = w * 128;
    v2f acc2[4];
#pragma unroll
    for (int q = 0; q < 4; ++q) acc2[q] = vsplat(0.f);
    const v2f* vp = reinterpret_cast<const v2f*>(value) +
                    ((size_t)b * 1024 + k0 + kb) * 64 + lane;
#pragma unroll 2
    for (int k4 = 0; k4 < 32; ++k4) {
      v2f vv0 = vp[(size_t)(k4 * 4 + 0) * 64];
      v2f vv1 = vp[(size_t)(k4 * 4 + 1) * 64];
      v2f vv2 = vp[(size_t)(k4 * 4 + 2) * 64];
      v2f vv3 = vp[(size_t)(k4 * 4 + 3) * 64];
#pragma unroll
      for (int q = 0; q < 4; ++q) {
        float4 pp = *reinterpret_cast<const float4*>(&sc[q][kb + k4 * 4]);
        acc2[q] = vfma(vsplat(pp.x), vv0, acc2[q]);
        acc2[q] = vfma(vsplat(pp.y), vv1, acc2[q]);
        acc2[q] = vfma(vsplat(pp.z), vv2, acc2[q]);
        acc2[q] = vfma(vsplat(pp.w), vv3, acc2[q]);
      }
    }
#pragma unroll
    for (int q = 0; q < 4; ++q) pout[w][q][lane] = acc2[q];
  }
  __syncthreads();

  // ---- 4-way cross-wave reduce -> workspace (unnormalized) ----
  {
    int q = tid >> 6;
    int c = tid & 63;
    v2f r = pout[0][q][c];
#pragma unroll
    for (int ww = 1; ww < 4; ++ww) r = r + pout[ww][q][c];
    *reinterpret_cast<v2f*>(pblk + (size_t)bi * 512 + q * 128 + 2 * c) = r;
  }
}

// Combine: sum the 2 k-half partials, normalize. 512 blocks x 256 threads;
// thread -> one (row, v2f col) of out[2048][128]. row wave-uniform -> s_load
// for dsum.
__global__ __launch_bounds__(256) void combine_kernel(
    const float* __restrict__ pblk, const float* __restrict__ dsum,
    float* __restrict__ out) {
  int g = blockIdx.x * 256 + threadIdx.x;
  int row = g >> 6;  // 0..2047, wave-uniform
  int c = g & 63;
  int q = row & 3;
  int bi0 = (row >> 2) * 2;  // (b*256+qg)*2
  v2f r0 = *reinterpret_cast<const v2f*>(pblk + (size_t)bi0 * 512 + q * 128 +
                                         2 * c);
  v2f r1 = *reinterpret_cast<const v2f*>(pblk + (size_t)(bi0 + 1) * 512 +
                                         q * 128 + 2 * c);
  float d = dsum[(size_t)bi0 * 4 + q] + dsum[(size_t)(bi0 + 1) * 4 + q];
  v2f r = r0 + r1;
  float inv = fast_rcp(d);
  r[0] *= inv;
  r[1] *= inv;
  *reinterpret_cast<v2f*>(out + (size_t)row * 128 + 2 * c) = r;
}

extern "C" void kernel_launch(void* const* d_in, const int* in_sizes, int n_in,
                              void* d_out, int out_size, void* d_ws,
                              size_t ws_size, hipStream_t stream) {
  const float* query = (const float*)d_in[0];
  const float* key = (const float*)d_in[1];
  const float* value = (const float*)d_in[2];
  const float* vT = (const float*)d_in[3];
  const float* weight = (const float*)d_in[4];
  float* out = (float*)d_out;
  float* Eq = (float*)d_ws;      // 2048*128 f32 = 1 MB
  float* EkT2 = Eq + 262144;     // 64 x 1024 x float4 = 1 MB (pair-interleaved)
  float* pblk = EkT2 + 262144;   // 1024 blocks x 4q x 128 f32 = 2 MB
  float* dsum = pblk + 524288;   // 1024 x 4 f32 = 16 KB
  proj_kernel<<<256, 256, 0, stream>>>(query, key, weight, Eq, EkT2);
  attn_kernel<<<1024, 256, 0, stream>>>(Eq, EkT2, vT, value, pblk, dsum);
  combine_kernel<<<512, 256, 0, stream>>>(pblk, dsum, out);
}